// Round 2
// 595.540 us; speedup vs baseline: 1.0775x; 1.0775x over previous
//
#include <hip/hip_runtime.h>
#include <stdint.h>

#define K_DIM 2048
#define N_DIM 2048
#define M_TOK 32768

typedef float v4f __attribute__((ext_vector_type(4)));
typedef int   v4i __attribute__((ext_vector_type(4)));

// ---------------- workspace layout (bytes) ----------------
// 0        : double wpart[1024]                  (8192 B)
// 8192     : float  wstat[2]  {winv, w_scale}
// 8448     : float  tscale[32768]                (131072 B, ends 139520)
// 262144   : int8   wt[2048*2048]   ternary      (4 MB, ends 4456448)
// 4456448  : int8   qx[32768*2048]  int8 values  (67 MB, ends 71565312)
#define WS_PART   0
#define WS_STAT   8192
#define WS_TSCALE 8448
#define WS_WT     262144
#define WS_QX     4456448

// ---------------- helpers ----------------
__device__ __forceinline__ void gload_lds16(const void* g, void* l) {
    __builtin_amdgcn_global_load_lds(
        (const __attribute__((address_space(1))) unsigned int*)g,
        (__attribute__((address_space(3))) unsigned int*)l,
        16, 0, 0);
}

__device__ __forceinline__ unsigned int pack4(int a, int b, int c, int d) {
    return (unsigned int)(a & 255) | ((unsigned int)(b & 255) << 8) |
           ((unsigned int)(c & 255) << 16) | ((unsigned int)(d & 255) << 24);
}

// ---------------- kernel 1: partial sum of |W| (double accum) ----------------
__global__ __launch_bounds__(256) void wabs_partial(const float* __restrict__ W,
                                                    double* __restrict__ part) {
    const int t = threadIdx.x, b = blockIdx.x;
    const float* p = W + (size_t)b * 4096;
    double s = 0.0;
#pragma unroll
    for (int i = 0; i < 4; ++i) {
        float4 v = *(const float4*)(p + i * 1024 + t * 4);
        s += (double)fabsf(v.x) + (double)fabsf(v.y) +
             (double)fabsf(v.z) + (double)fabsf(v.w);
    }
    int lane = t & 63, wv = t >> 6;
#pragma unroll
    for (int off = 32; off > 0; off >>= 1) s += __shfl_down(s, off, 64);
    __shared__ double red[4];
    if (lane == 0) red[wv] = s;
    __syncthreads();
    if (t == 0) part[b] = red[0] + red[1] + red[2] + red[3];
}

// ---------------- kernel 2: finalize w_scale ----------------
__global__ __launch_bounds__(256) void wfinal(const double* __restrict__ part,
                                              float* __restrict__ wstat) {
    const int t = threadIdx.x;
    double s = part[t] + part[t + 256] + part[t + 512] + part[t + 768];
    int lane = t & 63, wv = t >> 6;
#pragma unroll
    for (int off = 32; off > 0; off >>= 1) s += __shfl_down(s, off, 64);
    __shared__ double red[4];
    if (lane == 0) red[wv] = s;
    __syncthreads();
    if (t == 0) {
        double mean = (red[0] + red[1] + red[2] + red[3]) * (1.0 / 4194304.0);
        float winv = (float)mean + 1e-5f;        // = 1/w_scale
        wstat[0] = winv;
        wstat[1] = 1.0f / winv;                  // = w_scale
    }
}

// ---------------- kernel 3: quantize W -> ternary int8 ----------------
__global__ __launch_bounds__(256) void wquant(const float* __restrict__ W,
                                              const float* __restrict__ wstat,
                                              int8_t* __restrict__ wt) {
    const float wsc = wstat[1];
    size_t i = ((size_t)blockIdx.x * 256 + threadIdx.x) * 4;
    float4 v = *(const float4*)(W + i);
    int q0 = (int)rintf(fminf(fmaxf(v.x * wsc, -1.0f), 1.0f));
    int q1 = (int)rintf(fminf(fmaxf(v.y * wsc, -1.0f), 1.0f));
    int q2 = (int)rintf(fminf(fmaxf(v.z * wsc, -1.0f), 1.0f));
    int q3 = (int)rintf(fminf(fmaxf(v.w * wsc, -1.0f), 1.0f));
    *(unsigned int*)(wt + i) = pack4(q0, q1, q2, q3);
}

// ---------------- kernel 4: RMSNorm + per-token absmax int8 quant ----------------
__global__ __launch_bounds__(256) void rmsnorm_quant(const float* __restrict__ x,
                                                     const float* __restrict__ gamma,
                                                     const float* __restrict__ wstat,
                                                     int8_t* __restrict__ qx,
                                                     float* __restrict__ tscale) {
    const int row = blockIdx.x;
    const int t = threadIdx.x;
    const float* xr = x + (size_t)row * K_DIM;

    float4 v0 = *(const float4*)(xr + t * 4);
    float4 v1 = *(const float4*)(xr + 1024 + t * 4);
    float4 g0 = *(const float4*)(gamma + t * 4);
    float4 g1 = *(const float4*)(gamma + 1024 + t * 4);

    float ss = v0.x * v0.x + v0.y * v0.y + v0.z * v0.z + v0.w * v0.w +
               v1.x * v1.x + v1.y * v1.y + v1.z * v1.z + v1.w * v1.w;

    __shared__ float red[8];
    {
        int lane = t & 63, wv = t >> 6;
#pragma unroll
        for (int off = 32; off > 0; off >>= 1) ss += __shfl_down(ss, off, 64);
        if (lane == 0) red[wv] = ss;
        __syncthreads();
        ss = red[0] + red[1] + red[2] + red[3];
    }
    const float rms = 1.0f / sqrtf(ss * (1.0f / 2048.0f) + 1e-6f);

    float xn[8];
    xn[0] = v0.x * rms * g0.x;  xn[1] = v0.y * rms * g0.y;
    xn[2] = v0.z * rms * g0.z;  xn[3] = v0.w * rms * g0.w;
    xn[4] = v1.x * rms * g1.x;  xn[5] = v1.y * rms * g1.y;
    xn[6] = v1.z * rms * g1.z;  xn[7] = v1.w * rms * g1.w;

    float am = 0.0f;
#pragma unroll
    for (int j = 0; j < 8; ++j) am = fmaxf(am, fabsf(xn[j]));
    {
        int lane = t & 63, wv = t >> 6;
#pragma unroll
        for (int off = 32; off > 0; off >>= 1) am = fmaxf(am, __shfl_down(am, off, 64));
        if (lane == 0) red[4 + wv] = am;
        __syncthreads();
        am = fmaxf(fmaxf(red[4], red[5]), fmaxf(red[6], red[7]));
    }
    const float amp = am + 1e-5f;
    const float ascale = 127.0f / amp;

    int q[8];
#pragma unroll
    for (int j = 0; j < 8; ++j)
        q[j] = (int)rintf(fminf(fmaxf(xn[j] * ascale, -128.0f), 127.0f));

    int8_t* qr = qx + (size_t)row * K_DIM;
    *(unsigned int*)(qr + t * 4)        = pack4(q[0], q[1], q[2], q[3]);
    *(unsigned int*)(qr + 1024 + t * 4) = pack4(q[4], q[5], q[6], q[7]);

    if (t == 0) tscale[row] = amp * wstat[0] * (1.0f / 127.0f);
}

// ---------------- kernel 5: i8 MFMA GEMM, 256x256 tile, 8-phase pipeline ----
// C[m,n] = tscale[m] * sum_k qx[m,k] * wt[n,k]   (both operands K-major, int8)
//
// Structure (T2+T3+T4+T5 from the technique catalog):
//   BM=BN=256, BK=128 B, 8 waves (2M x 4N), per-wave 128x64 output.
//   LDS: ldsA[2][256][128] + ldsB[2][256][128] = 128 KiB (double-buffered).
//   2 K-tiles per iteration, 8 phases; each phase = {ds_read quadrant frags,
//   issue 1 half-tile (2 x global_load_lds_dwordx4), s_barrier, lgkmcnt(0),
//   setprio(1), 16 MFMA, setprio(0), [vmcnt(4) at ph3/ph7], s_barrier}.
//   vmcnt never drains to 0 in the main loop (counted protocol):
//     ph0: (2i+1).A-lo -> buf1   ph4: (2i+2).A-lo -> buf0
//     ph1: (2i+1).A-hi -> buf1   ph5: (2i+2).A-hi -> buf0
//     ph2: (2i+2).B-lo -> buf0   ph6: (2i+3).B-lo -> buf1
//     ph3: (2i+2).B-hi -> buf0   ph7: (2i+3).B-hi -> buf1
//   WAR ledger: B-halves of a buffer die after its q=0 phase (regs), A-halves
//   after its q=3 phase; every issue above lands >=1 full barrier after the
//   corresponding death.  vmcnt(4) at ph3 leaves ph2/ph3 in flight and proves
//   (2i+1).{A,B} landed; vmcnt(4) at ph7 leaves ph6/ph7 in flight and proves
//   (2i+2).{A,B} landed.  Last iteration: ph2..ph7 issues predicated off,
//   ph3 drains vmcnt(0) (tail only).
//   LDS XOR-swizzle (chunk ^= row&7) carried over: linear gload_lds dest +
//   inverse-swizzled global source + swizzled ds_read (both-sides rule #21).

__device__ __forceinline__ v4i ldsfrag(const int8_t* p, int row, int j0) {
    return *(const v4i*)(p + row * 128 + (((j0) ^ (row & 7)) << 4));
}

template <int Q, bool LOADB>
__device__ __forceinline__ void ph_load(const int8_t* pA, const int8_t* pB,
                                        v4i (&af)[2][2], v4i (&bf)[4][2],
                                        int wm, int wn, int l16, int quad) {
    if constexpr (LOADB) {
#pragma unroll
        for (int nt = 0; nt < 4; ++nt)
#pragma unroll
            for (int ks = 0; ks < 2; ++ks)
                bf[nt][ks] = ldsfrag(pB, wn + nt * 16 + l16, ks * 4 + quad);
    }
#pragma unroll
    for (int mt = 0; mt < 2; ++mt)
#pragma unroll
        for (int ks = 0; ks < 2; ++ks)
            af[mt][ks] = ldsfrag(pA, wm + (2 * Q + mt) * 16 + l16, ks * 4 + quad);
}

template <int Q>
__device__ __forceinline__ void ph_mma(v4i (&acc)[8][4], const v4i (&af)[2][2],
                                       const v4i (&bf)[4][2]) {
#pragma unroll
    for (int mt = 0; mt < 2; ++mt)
#pragma unroll
        for (int nt = 0; nt < 4; ++nt)
#pragma unroll
            for (int ks = 0; ks < 2; ++ks)
                acc[2 * Q + mt][nt] = __builtin_amdgcn_mfma_i32_16x16x64_i8(
                    af[mt][ks], bf[nt][ks], acc[2 * Q + mt][nt], 0, 0, 0);
}

#define VMC(n) asm volatile("s_waitcnt vmcnt(" #n ")" ::: "memory")

__global__ __launch_bounds__(512, 2) void gemm_i8(const int8_t* __restrict__ qx,
                                                  const int8_t* __restrict__ wt,
                                                  const float* __restrict__ tscale,
                                                  float* __restrict__ out) {
    __shared__ int8_t ldsA[2][32768];
    __shared__ int8_t ldsB[2][32768];

    const int t = threadIdx.x;          // 0..511
    const int lane = t & 63;
    const int w = t >> 6;               // wave 0..7
    const int l16 = lane & 15;
    const int quad = lane >> 4;

    // bijective XCD swizzle: nwg=1024, 8 XCDs -> XCD x owns swz in [x*128,x*128+128)
    const int bid = blockIdx.x;
    const int swz = (bid & 7) * 128 + (bid >> 3);
    const int bn0 = (swz & 7) * 256;    // 8 N-tiles (fast within XCD: shares A panel)
    const int bm0 = (swz >> 3) * 256;   // 128 M-tiles

    const int wm = (w >> 2) * 128;      // 0 | 128
    const int wn = (w & 3) * 64;        // 0 | 64 | 128 | 192

    // staging geometry: thread t covers 16B chunk c=t (s=0) and c=t+512 (s=1)
    // of a 16KB half-tile; row = c>>3, chunk j = c&7, stored chunk j holds
    // global chunk j^(row&7).  s=1 is row+64 with identical swizzle (64%8==0).
    const int srow = t >> 3;                       // 0..63
    const int sjx  = ((t & 7) ^ (srow & 7)) << 4;  // swizzled byte offset in row
    const int wbase = w * 1024;                    // wave-uniform LDS base
    const size_t baseA = (size_t)bm0 * K_DIM;
    const size_t baseB = (size_t)bn0 * K_DIM;

#define STAGE_A(buf, h, kt) do {                                                   \
        const int8_t* _s = qx + baseA + (size_t)((h) * 128 + srow) * K_DIM +       \
                           (kt) * 128 + sjx;                                       \
        gload_lds16(_s,              &ldsA[buf][(h) * 16384 + wbase]);             \
        gload_lds16(_s + 64 * K_DIM, &ldsA[buf][(h) * 16384 + 8192 + wbase]);      \
    } while (0)
#define STAGE_B(buf, h, kt) do {                                                   \
        const int8_t* _s = wt + baseB + (size_t)((h) * 128 + srow) * K_DIM +       \
                           (kt) * 128 + sjx;                                       \
        gload_lds16(_s,              &ldsB[buf][(h) * 16384 + wbase]);             \
        gload_lds16(_s + 64 * K_DIM, &ldsB[buf][(h) * 16384 + 8192 + wbase]);      \
    } while (0)

    v4i acc[8][4];
    const v4i izero = {0, 0, 0, 0};
#pragma unroll
    for (int i = 0; i < 8; ++i)
#pragma unroll
        for (int j = 0; j < 4; ++j) acc[i][j] = izero;

    v4i bf[4][2];
    const int8_t* pA0 = ldsA[0];
    const int8_t* pA1 = ldsA[1];
    const int8_t* pB0 = ldsB[0];
    const int8_t* pB1 = ldsB[1];

    // ---- prologue: K-tile 0 (B,A) + K-tile 1 (B); vmcnt(4) proves K0 landed
    STAGE_B(0, 0, 0);
    STAGE_B(0, 1, 0);
    STAGE_A(0, 0, 0);
    STAGE_A(0, 1, 0);
    STAGE_B(1, 0, 1);
    STAGE_B(1, 1, 1);
    VMC(4);
    __builtin_amdgcn_s_barrier();

#define DO_PHASE(Q, LOADB, PA, PB, STAGE_STMT, TAIL_STMT)           \
    {                                                               \
        v4i af[2][2];                                               \
        ph_load<Q, LOADB>(PA, PB, af, bf, wm, wn, l16, quad);       \
        STAGE_STMT;                                                 \
        __builtin_amdgcn_s_barrier();                               \
        asm volatile("s_waitcnt lgkmcnt(0)" ::: "memory");          \
        __builtin_amdgcn_sched_barrier(0);                          \
        __builtin_amdgcn_s_setprio(1);                              \
        ph_mma<Q>(acc, af, bf);                                     \
        __builtin_amdgcn_s_setprio(0);                              \
        TAIL_STMT;                                                  \
        __builtin_amdgcn_s_barrier();                               \
    }

#pragma unroll 1
    for (int i = 0; i < 8; ++i) {
        const int kt1 = 2 * i + 1;
        const int kt2 = 2 * i + 2;
        const int kt3 = 2 * i + 3;
        const bool pf = (i < 7);
        // K-tile 2i (buffer 0)
        DO_PHASE(0, true,  pA0, pB0, STAGE_A(1, 0, kt1), (void)0);
        DO_PHASE(1, false, pA0, pB0, STAGE_A(1, 1, kt1), (void)0);
        DO_PHASE(2, false, pA0, pB0, if (pf) STAGE_B(0, 0, kt2), (void)0);
        DO_PHASE(3, false, pA0, pB0, if (pf) STAGE_B(0, 1, kt2),
                 if (pf) { VMC(4); } else { VMC(0); });
        // K-tile 2i+1 (buffer 1)
        DO_PHASE(0, true,  pA1, pB1, if (pf) STAGE_A(0, 0, kt2), (void)0);
        DO_PHASE(1, false, pA1, pB1, if (pf) STAGE_A(0, 1, kt2), (void)0);
        DO_PHASE(2, false, pA1, pB1, if (pf) STAGE_B(1, 0, kt3), (void)0);
        DO_PHASE(3, false, pA1, pB1, if (pf) STAGE_B(1, 1, kt3), VMC(4));
    }

    // epilogue: D layout col=lane&15, row=quad*4+r (dtype-independent, m121-128)
#pragma unroll
    for (int mt = 0; mt < 8; ++mt) {
#pragma unroll
        for (int r = 0; r < 4; ++r) {
            const int row = bm0 + wm + mt * 16 + quad * 4 + r;
            const float s = tscale[row];
            float* op = out + (size_t)row * N_DIM + bn0 + wn + l16;
#pragma unroll
            for (int nt = 0; nt < 4; ++nt)
                op[nt * 16] = (float)acc[mt][nt][r] * s;
        }
    }
#undef DO_PHASE
#undef STAGE_A
#undef STAGE_B
}

// ---------------- launch ----------------
extern "C" void kernel_launch(void* const* d_in, const int* in_sizes, int n_in,
                              void* d_out, int out_size, void* d_ws, size_t ws_size,
                              hipStream_t stream) {
    const float* x     = (const float*)d_in[0];
    const float* gamma = (const float*)d_in[1];
    const float* W     = (const float*)d_in[2];
    float* out = (float*)d_out;

    char* ws = (char*)d_ws;
    double* wpart  = (double*)(ws + WS_PART);
    float*  wstat  = (float*)(ws + WS_STAT);
    float*  tscale = (float*)(ws + WS_TSCALE);
    int8_t* wt     = (int8_t*)(ws + WS_WT);
    int8_t* qx     = (int8_t*)(ws + WS_QX);

    wabs_partial<<<1024, 256, 0, stream>>>(W, wpart);
    wfinal<<<1, 256, 0, stream>>>(wpart, wstat);
    wquant<<<4096, 256, 0, stream>>>(W, wstat, wt);
    rmsnorm_quant<<<M_TOK, 256, 0, stream>>>(x, gamma, wstat, qx, tscale);

    gemm_i8<<<dim3(1024), dim3(512), 0, stream>>>(qx, wt, tscale, out);
}